// Round 1
// baseline (557.857 us; speedup 1.0000x reference)
//
#include <hip/hip_runtime.h>
#include <stdint.h>

// ---------------------------------------------------------------------------
// CrossAttentionRope: x(16,256,768), ctx(16,4096,768) f32 -> out(16,256,768) f32
// Pipeline: cvt->bf16, W^T, GEMM(K+rope), GEMM(V->V^T), GEMM(Q+rope+scale),
//           flash-attn, GEMM(O @ Wo) -> f32.
// All MFMA bf16 16x16x32, f32 accum. LDS XOR chunk-swizzle (T2) everywhere.
// ---------------------------------------------------------------------------

typedef __bf16 bf16x8 __attribute__((ext_vector_type(8)));
typedef float f32x4 __attribute__((ext_vector_type(4)));

#define DIMF 768
#define NHEAD 12
#define NKV 4096
#define NQ 256
#define NB 16

struct alignas(8) us4 { unsigned short x, y, z, w; };

__device__ __forceinline__ unsigned short f2bf(float x) {
  uint32_t u = __float_as_uint(x);
  u += 0x7fffu + ((u >> 16) & 1u);   // round-to-nearest-even
  return (unsigned short)(u >> 16);
}

// ---------------- convert f32 -> bf16 (vectorized, grid-stride) ------------
__global__ void cvt_kernel(const float* __restrict__ in, unsigned short* __restrict__ out, int n) {
  int stride = gridDim.x * blockDim.x * 4;
  for (int i = (blockIdx.x * blockDim.x + threadIdx.x) * 4; i < n; i += stride) {
    float4 v = *(const float4*)(in + i);
    us4 o{f2bf(v.x), f2bf(v.y), f2bf(v.z), f2bf(v.w)};
    *(us4*)(out + i) = o;
  }
}

// ---------------- weight transpose + cvt: Wt[n][k] = W[k][n] ---------------
__global__ void twt_kernel(const float* __restrict__ W0, const float* __restrict__ W1,
                           const float* __restrict__ W2, const float* __restrict__ W3,
                           unsigned short* __restrict__ O0, unsigned short* __restrict__ O1,
                           unsigned short* __restrict__ O2, unsigned short* __restrict__ O3) {
  const float* W; unsigned short* O;
  switch (blockIdx.z) {
    case 0: W = W0; O = O0; break;
    case 1: W = W1; O = O1; break;
    case 2: W = W2; O = O2; break;
    default: W = W3; O = O3; break;
  }
  __shared__ float t[32][33];
  int x0 = blockIdx.x * 32, y0 = blockIdx.y * 32;
  int tx = threadIdx.x, ty = threadIdx.y;
#pragma unroll
  for (int j = 0; j < 4; ++j)
    t[ty + 8 * j][tx] = W[(size_t)(y0 + ty + 8 * j) * DIMF + x0 + tx];
  __syncthreads();
#pragma unroll
  for (int j = 0; j < 4; ++j)
    O[(size_t)(x0 + ty + 8 * j) * DIMF + y0 + tx] = f2bf(t[tx][ty + 8 * j]);
}

// ---------------- GEMM: C(128x128 tile) = A(Mx768) * Bt(768x768)^T ----------
// MODE 0: K-proj (+rope_k)  -> K  [b][h][n][64]    bf16
// MODE 1: V-proj            -> Vt [b][h][64][4096] bf16
// MODE 2: Q-proj (+rope_q, *0.125) -> Q [b][h][nq][64] bf16
// MODE 3: O-proj            -> out f32 [p][768]
template <int MODE>
__launch_bounds__(256, 2)
__global__ void gemm_kernel(const unsigned short* __restrict__ A,
                            const unsigned short* __restrict__ Bt,
                            void* __restrict__ outp,
                            const float* __restrict__ rope) {
  __shared__ unsigned short As[128 * 64];
  __shared__ unsigned short Bs[128 * 64];
  const int t = threadIdx.x;
  const int lane = t & 63, wid = t >> 6;
  const int g = lane >> 4, lc = lane & 15;
  const int wr = wid >> 1, wc = wid & 1;
  const int rowBase = blockIdx.x * 128, colBase = blockIdx.y * 128;

  const f32x4 z4 = {0.f, 0.f, 0.f, 0.f};
  f32x4 acc[4][4];
#pragma unroll
  for (int m = 0; m < 4; ++m)
#pragma unroll
    for (int n = 0; n < 4; ++n) acc[m][n] = z4;

  const int r0 = t >> 3;   // 0..31
  const int c0 = t & 7;    // 16B chunk within 128B row

  bf16x8 ra[4], rb[4];
#pragma unroll
  for (int pp = 0; pp < 4; ++pp) {
    int row = pp * 32 + r0;
    ra[pp] = *(const bf16x8*)(A + (size_t)(rowBase + row) * DIMF + c0 * 8);
    rb[pp] = *(const bf16x8*)(Bt + (size_t)(colBase + row) * DIMF + c0 * 8);
  }

  for (int kb = 0; kb < 12; ++kb) {
    __syncthreads();
#pragma unroll
    for (int pp = 0; pp < 4; ++pp) {
      int row = pp * 32 + r0;
      int ph = ((c0 ^ (row & 7)) << 3);
      *(bf16x8*)&As[row * 64 + ph] = ra[pp];
      *(bf16x8*)&Bs[row * 64 + ph] = rb[pp];
    }
    __syncthreads();
    if (kb + 1 < 12) {
      int kn = (kb + 1) * 64;
#pragma unroll
      for (int pp = 0; pp < 4; ++pp) {
        int row = pp * 32 + r0;
        ra[pp] = *(const bf16x8*)(A + (size_t)(rowBase + row) * DIMF + kn + c0 * 8);
        rb[pp] = *(const bf16x8*)(Bt + (size_t)(colBase + row) * DIMF + kn + c0 * 8);
      }
    }
#pragma unroll
    for (int kk = 0; kk < 2; ++kk) {
      bf16x8 af[4], bfr[4];
#pragma unroll
      for (int m = 0; m < 4; ++m) {
        int row = wr * 64 + m * 16 + lc;
        int ch = kk * 4 + g;
        af[m] = *(const bf16x8*)&As[row * 64 + (((ch ^ (row & 7))) << 3)];
      }
#pragma unroll
      for (int n = 0; n < 4; ++n) {
        int row = wc * 64 + n * 16 + lc;
        int ch = kk * 4 + g;
        bfr[n] = *(const bf16x8*)&Bs[row * 64 + (((ch ^ (row & 7))) << 3)];
      }
#pragma unroll
      for (int m = 0; m < 4; ++m)
#pragma unroll
        for (int n = 0; n < 4; ++n)
          acc[m][n] = __builtin_amdgcn_mfma_f32_16x16x32_bf16(af[m], bfr[n], acc[m][n], 0, 0, 0);
    }
  }

  // ---- epilogue (C/D frag: col = lc, row = g*4 + reg) ----
  if (MODE == 0 || MODE == 2) {
    unsigned short* Ko = (unsigned short*)outp;
#pragma unroll
    for (int m = 0; m < 4; ++m)
#pragma unroll
      for (int n = 0; n < 4; ++n)
#pragma unroll
        for (int r = 0; r < 4; ++r) {
          int p = rowBase + wr * 64 + m * 16 + g * 4 + r;
          int f = colBase + wc * 64 + n * 16 + lc;
          int d = f & 63, h = f >> 6;
          float v = acc[m][n][r];
          float vo = __shfl_xor(v, 1);
          if (MODE == 0) {
            int b = p >> 12, nkv = p & 4095;
            float sn = rope[nkv * 128 + d], cs = rope[nkv * 128 + 64 + d];
            float o = (d & 1) ? fmaf(vo, sn, v * cs) : fmaf(-vo, sn, v * cs);
            Ko[((size_t)(b * NHEAD + h) * NKV + nkv) * 64 + d] = f2bf(o);
          } else {
            int b = p >> 8, nq = p & 255;
            float sn = rope[nq * 128 + d], cs = rope[nq * 128 + 64 + d];
            float o = (d & 1) ? fmaf(vo, sn, v * cs) : fmaf(-vo, sn, v * cs);
            Ko[((size_t)(b * NHEAD + h) * NQ + nq) * 64 + d] = f2bf(o * 0.125f);
          }
        }
  } else if (MODE == 1) {
    unsigned short* Vt = (unsigned short*)outp;
#pragma unroll
    for (int m = 0; m < 4; ++m)
#pragma unroll
      for (int n = 0; n < 4; ++n) {
        int p0 = rowBase + wr * 64 + m * 16 + g * 4;   // 4 consecutive rows
        int b = p0 >> 12, nkv0 = p0 & 4095;
        int f = colBase + wc * 64 + n * 16 + lc;
        int d = f & 63, h = f >> 6;
        us4 w{f2bf(acc[m][n][0]), f2bf(acc[m][n][1]), f2bf(acc[m][n][2]), f2bf(acc[m][n][3])};
        *(us4*)&Vt[((size_t)(b * NHEAD + h) * 64 + d) * NKV + nkv0] = w;
      }
  } else {
    float* Co = (float*)outp;
#pragma unroll
    for (int m = 0; m < 4; ++m)
#pragma unroll
      for (int n = 0; n < 4; ++n)
#pragma unroll
        for (int r = 0; r < 4; ++r) {
          int p = rowBase + wr * 64 + m * 16 + g * 4 + r;
          int f = colBase + wc * 64 + n * 16 + lc;
          Co[(size_t)p * DIMF + f] = acc[m][n][r];
        }
  }
}

// ---------------- flash attention ------------------------------------------
// grid.x = 384: qt = bid&1 (128-row q tile), bh = bid>>1. 4 waves x 32 q-rows.
__launch_bounds__(256, 2)
__global__ void attn_kernel(const unsigned short* __restrict__ Qb,
                            const unsigned short* __restrict__ Kb,
                            const unsigned short* __restrict__ Vtb,
                            unsigned short* __restrict__ Ob) {
  __shared__ unsigned short Ks[128 * 64];    // [kv][d]  (swizzled chunks)
  __shared__ unsigned short Vts[64 * 128];   // [d][kv]
  __shared__ unsigned short Ps[4][32 * 128]; // per-wave P [qrow][kv]
  const int bid = blockIdx.x;
  const int qt = bid & 1, bh = bid >> 1;
  const int b = bh / NHEAD, h = bh % NHEAD;
  const int t = threadIdx.x;
  const int lane = t & 63, wid = t >> 6;
  const int g = lane >> 4, lc = lane & 15;
  const int qbase = qt * 128;

  const f32x4 z4 = {0.f, 0.f, 0.f, 0.f};
  bf16x8 qf[2][2];
#pragma unroll
  for (int m = 0; m < 2; ++m)
#pragma unroll
    for (int kk = 0; kk < 2; ++kk) {
      int row = qbase + wid * 32 + m * 16 + lc;
      qf[m][kk] = *(const bf16x8*)(Qb + ((size_t)bh * NQ + row) * 64 + kk * 32 + g * 8);
    }

  f32x4 oacc[2][4];
  float mrun[2][4], lrun[2][4];
#pragma unroll
  for (int m = 0; m < 2; ++m)
#pragma unroll
    for (int r = 0; r < 4; ++r) { mrun[m][r] = -1e30f; lrun[m][r] = 0.f; }
#pragma unroll
  for (int m = 0; m < 2; ++m)
#pragma unroll
    for (int n = 0; n < 4; ++n) oacc[m][n] = z4;

  for (int kt = 0; kt < 32; ++kt) {
    const int kvbase = kt * 128;
    __syncthreads();
    // stage K tile [128][64]
#pragma unroll
    for (int pp = 0; pp < 4; ++pp) {
      int row = pp * 32 + (t >> 3);
      int ch = t & 7;
      bf16x8 v = *(const bf16x8*)(Kb + ((size_t)bh * NKV + kvbase + row) * 64 + ch * 8);
      *(bf16x8*)&Ks[row * 64 + ((ch ^ (row & 7)) << 3)] = v;
    }
    // stage Vt tile [64][128]
#pragma unroll
    for (int pp = 0; pp < 4; ++pp) {
      int d = pp * 16 + (t >> 4);
      int ch = t & 15;
      bf16x8 v = *(const bf16x8*)(Vtb + ((size_t)bh * 64 + d) * NKV + kvbase + ch * 8);
      *(bf16x8*)&Vts[d * 128 + ((ch ^ (d & 7)) << 3)] = v;
    }
    __syncthreads();

    // S = Q K^T   (per wave: 32 rows x 128 cols)
    f32x4 s[2][8];
#pragma unroll
    for (int m = 0; m < 2; ++m)
#pragma unroll
      for (int nf = 0; nf < 8; ++nf) s[m][nf] = z4;
#pragma unroll
    for (int kk = 0; kk < 2; ++kk)
#pragma unroll
      for (int nf = 0; nf < 8; ++nf) {
        int row = nf * 16 + lc;
        int ch = kk * 4 + g;
        bf16x8 kf = *(const bf16x8*)&Ks[row * 64 + ((ch ^ (row & 7)) << 3)];
#pragma unroll
        for (int m = 0; m < 2; ++m)
          s[m][nf] = __builtin_amdgcn_mfma_f32_16x16x32_bf16(qf[m][kk], kf, s[m][nf], 0, 0, 0);
      }

    // online softmax per row; write P (bf16) to wave-private LDS
#pragma unroll
    for (int m = 0; m < 2; ++m) {
      float mx[4];
#pragma unroll
      for (int r = 0; r < 4; ++r) {
        float v = s[m][0][r];
#pragma unroll
        for (int nf = 1; nf < 8; ++nf) v = fmaxf(v, s[m][nf][r]);
        mx[r] = v;
      }
#pragma unroll
      for (int r = 0; r < 4; ++r) {
        mx[r] = fmaxf(mx[r], __shfl_xor(mx[r], 1));
        mx[r] = fmaxf(mx[r], __shfl_xor(mx[r], 2));
        mx[r] = fmaxf(mx[r], __shfl_xor(mx[r], 4));
        mx[r] = fmaxf(mx[r], __shfl_xor(mx[r], 8));
      }
#pragma unroll
      for (int r = 0; r < 4; ++r) {
        float nm = fmaxf(mrun[m][r], mx[r]);
        float al = __expf(mrun[m][r] - nm);
        mrun[m][r] = nm;
        float ls = 0.f;
#pragma unroll
        for (int nf = 0; nf < 8; ++nf) {
          float p = __expf(s[m][nf][r] - nm);
          s[m][nf][r] = p;
          ls += p;
        }
        ls += __shfl_xor(ls, 1);
        ls += __shfl_xor(ls, 2);
        ls += __shfl_xor(ls, 4);
        ls += __shfl_xor(ls, 8);
        lrun[m][r] = lrun[m][r] * al + ls;
#pragma unroll
        for (int nf = 0; nf < 4; ++nf) oacc[m][nf][r] *= al;
      }
#pragma unroll
      for (int nf = 0; nf < 8; ++nf)
#pragma unroll
        for (int r = 0; r < 4; ++r) {
          int rowl = m * 16 + g * 4 + r;
          int col = nf * 16 + lc;
          int ch = col >> 3;
          Ps[wid][rowl * 128 + ((ch ^ (rowl & 7)) << 3) + (col & 7)] = f2bf(s[m][nf][r]);
        }
    }
    __syncthreads();

    // O += P V   (A from Ps, B from Vts)
#pragma unroll
    for (int kk = 0; kk < 4; ++kk) {
      bf16x8 pa[2];
#pragma unroll
      for (int m = 0; m < 2; ++m) {
        int row = m * 16 + lc;
        int ch = kk * 4 + g;
        pa[m] = *(const bf16x8*)&Ps[wid][row * 128 + ((ch ^ (row & 7)) << 3)];
      }
#pragma unroll
      for (int nf = 0; nf < 4; ++nf) {
        int row = nf * 16 + lc;
        int ch = kk * 4 + g;
        bf16x8 vf = *(const bf16x8*)&Vts[row * 128 + ((ch ^ (row & 7)) << 3)];
#pragma unroll
        for (int m = 0; m < 2; ++m)
          oacc[m][nf] = __builtin_amdgcn_mfma_f32_16x16x32_bf16(pa[m], vf, oacc[m][nf], 0, 0, 0);
      }
    }
  }

  // epilogue: normalize, write O [b][q][h*64+d] bf16
#pragma unroll
  for (int m = 0; m < 2; ++m) {
    float inv[4];
#pragma unroll
    for (int r = 0; r < 4; ++r) inv[r] = 1.0f / lrun[m][r];
#pragma unroll
    for (int nf = 0; nf < 4; ++nf)
#pragma unroll
      for (int r = 0; r < 4; ++r) {
        int q = qbase + wid * 32 + m * 16 + g * 4 + r;
        int col = h * 64 + nf * 16 + lc;
        Ob[((size_t)b * NQ + q) * DIMF + col] = f2bf(oacc[m][nf][r] * inv[r]);
      }
  }
}

// ---------------- launch ----------------------------------------------------
extern "C" void kernel_launch(void* const* d_in, const int* in_sizes, int n_in,
                              void* d_out, int out_size, void* d_ws, size_t ws_size,
                              hipStream_t stream) {
  const float* x      = (const float*)d_in[0];
  const float* ctx    = (const float*)d_in[1];
  const float* rope_q = (const float*)d_in[2];
  const float* rope_k = (const float*)d_in[3];
  const float* Wq     = (const float*)d_in[4];
  const float* Wk     = (const float*)d_in[5];
  const float* Wv     = (const float*)d_in[6];
  const float* Wo     = (const float*)d_in[7];

  char* ws = (char*)d_ws;
  // workspace layout (bytes)
  const size_t SZ_CTXB = (size_t)NB * NKV * DIMF * 2;   // 100,663,296
  const size_t SZ_XB   = (size_t)NB * NQ * DIMF * 2;    // 6,291,456
  const size_t SZ_WT   = (size_t)DIMF * DIMF * 2;       // 1,179,648
  unsigned short* ctxb = (unsigned short*)(ws);
  unsigned short* ob   = (unsigned short*)(ws);                       // alias ctxb (dead after V-GEMM)
  unsigned short* xb   = (unsigned short*)(ws + SZ_CTXB);
  unsigned short* wkt  = (unsigned short*)(ws + SZ_CTXB + SZ_XB);
  unsigned short* wvt  = (unsigned short*)(ws + SZ_CTXB + SZ_XB + SZ_WT);
  unsigned short* wqt  = (unsigned short*)(ws + SZ_CTXB + SZ_XB + 2 * SZ_WT);
  unsigned short* wot  = (unsigned short*)(ws + SZ_CTXB + SZ_XB + 3 * SZ_WT);
  unsigned short* kb   = (unsigned short*)(ws + SZ_CTXB + SZ_XB + 4 * SZ_WT);
  unsigned short* vtb  = (unsigned short*)(ws + SZ_CTXB + SZ_XB + 4 * SZ_WT + SZ_CTXB);
  unsigned short* qb   = (unsigned short*)(ws + SZ_CTXB + SZ_XB + 4 * SZ_WT + 2 * SZ_CTXB);

  cvt_kernel<<<dim3(2048), dim3(256), 0, stream>>>(ctx, ctxb, NB * NKV * DIMF);
  cvt_kernel<<<dim3(1024), dim3(256), 0, stream>>>(x, xb, NB * NQ * DIMF);
  twt_kernel<<<dim3(24, 24, 4), dim3(32, 8), 0, stream>>>(Wk, Wv, Wq, Wo, wkt, wvt, wqt, wot);

  gemm_kernel<0><<<dim3(512, 6), dim3(256), 0, stream>>>(ctxb, wkt, kb, rope_k);
  gemm_kernel<1><<<dim3(512, 6), dim3(256), 0, stream>>>(ctxb, wvt, vtb, nullptr);
  gemm_kernel<2><<<dim3(32, 6), dim3(256), 0, stream>>>(xb, wqt, qb, rope_q);

  attn_kernel<<<dim3(384), dim3(256), 0, stream>>>(qb, kb, vtb, ob);

  gemm_kernel<3><<<dim3(32, 6), dim3(256), 0, stream>>>(ob, wot, d_out, nullptr);
}

// Round 2
// 481.062 us; speedup vs baseline: 1.1596x; 1.1596x over previous
//
#include <hip/hip_runtime.h>
#include <stdint.h>

// ---------------------------------------------------------------------------
// CrossAttentionRope: x(16,256,768), ctx(16,4096,768) f32 -> out(16,256,768) f32
// Pipeline: cvt->bf16, W^T, GEMM(K+rope), GEMM(V->V^T), GEMM(Q+rope+scale),
//           flash-attn, GEMM(O @ Wo) -> f32.
// All MFMA bf16 16x16x32, f32 accum. LDS XOR chunk-swizzle (T2) everywhere.
// R2: attn rewritten — 2-wave blocks (q-tile 64), grid 768, LDS 40KB
//     (4 blocks/CU), T14 reg-prefetch of K/V, m-split Ps, 2 barriers/tile,
//     XCD-bijective block swizzle.
// ---------------------------------------------------------------------------

typedef __bf16 bf16x8 __attribute__((ext_vector_type(8)));
typedef float f32x4 __attribute__((ext_vector_type(4)));

#define DIMF 768
#define NHEAD 12
#define NKV 4096
#define NQ 256
#define NB 16

struct alignas(8) us4 { unsigned short x, y, z, w; };

__device__ __forceinline__ unsigned short f2bf(float x) {
  uint32_t u = __float_as_uint(x);
  u += 0x7fffu + ((u >> 16) & 1u);   // round-to-nearest-even
  return (unsigned short)(u >> 16);
}

// ---------------- convert f32 -> bf16 (vectorized, grid-stride) ------------
__global__ void cvt_kernel(const float* __restrict__ in, unsigned short* __restrict__ out, int n) {
  int stride = gridDim.x * blockDim.x * 4;
  for (int i = (blockIdx.x * blockDim.x + threadIdx.x) * 4; i < n; i += stride) {
    float4 v = *(const float4*)(in + i);
    us4 o{f2bf(v.x), f2bf(v.y), f2bf(v.z), f2bf(v.w)};
    *(us4*)(out + i) = o;
  }
}

// ---------------- weight transpose + cvt: Wt[n][k] = W[k][n] ---------------
__global__ void twt_kernel(const float* __restrict__ W0, const float* __restrict__ W1,
                           const float* __restrict__ W2, const float* __restrict__ W3,
                           unsigned short* __restrict__ O0, unsigned short* __restrict__ O1,
                           unsigned short* __restrict__ O2, unsigned short* __restrict__ O3) {
  const float* W; unsigned short* O;
  switch (blockIdx.z) {
    case 0: W = W0; O = O0; break;
    case 1: W = W1; O = O1; break;
    case 2: W = W2; O = O2; break;
    default: W = W3; O = O3; break;
  }
  __shared__ float t[32][33];
  int x0 = blockIdx.x * 32, y0 = blockIdx.y * 32;
  int tx = threadIdx.x, ty = threadIdx.y;
#pragma unroll
  for (int j = 0; j < 4; ++j)
    t[ty + 8 * j][tx] = W[(size_t)(y0 + ty + 8 * j) * DIMF + x0 + tx];
  __syncthreads();
#pragma unroll
  for (int j = 0; j < 4; ++j)
    O[(size_t)(x0 + ty + 8 * j) * DIMF + y0 + tx] = f2bf(t[tx][ty + 8 * j]);
}

// ---------------- GEMM: C(128x128 tile) = A(Mx768) * Bt(768x768)^T ----------
// MODE 0: K-proj (+rope_k)  -> K  [b][h][n][64]    bf16
// MODE 1: V-proj            -> Vt [b][h][64][4096] bf16
// MODE 2: Q-proj (+rope_q, *0.125) -> Q [b][h][nq][64] bf16
// MODE 3: O-proj            -> out f32 [p][768]
template <int MODE>
__launch_bounds__(256, 2)
__global__ void gemm_kernel(const unsigned short* __restrict__ A,
                            const unsigned short* __restrict__ Bt,
                            void* __restrict__ outp,
                            const float* __restrict__ rope) {
  __shared__ unsigned short As[128 * 64];
  __shared__ unsigned short Bs[128 * 64];
  const int t = threadIdx.x;
  const int lane = t & 63, wid = t >> 6;
  const int g = lane >> 4, lc = lane & 15;
  const int wr = wid >> 1, wc = wid & 1;
  const int rowBase = blockIdx.x * 128, colBase = blockIdx.y * 128;

  const f32x4 z4 = {0.f, 0.f, 0.f, 0.f};
  f32x4 acc[4][4];
#pragma unroll
  for (int m = 0; m < 4; ++m)
#pragma unroll
    for (int n = 0; n < 4; ++n) acc[m][n] = z4;

  const int r0 = t >> 3;   // 0..31
  const int c0 = t & 7;    // 16B chunk within 128B row

  bf16x8 ra[4], rb[4];
#pragma unroll
  for (int pp = 0; pp < 4; ++pp) {
    int row = pp * 32 + r0;
    ra[pp] = *(const bf16x8*)(A + (size_t)(rowBase + row) * DIMF + c0 * 8);
    rb[pp] = *(const bf16x8*)(Bt + (size_t)(colBase + row) * DIMF + c0 * 8);
  }

  for (int kb = 0; kb < 12; ++kb) {
    __syncthreads();
#pragma unroll
    for (int pp = 0; pp < 4; ++pp) {
      int row = pp * 32 + r0;
      int ph = ((c0 ^ (row & 7)) << 3);
      *(bf16x8*)&As[row * 64 + ph] = ra[pp];
      *(bf16x8*)&Bs[row * 64 + ph] = rb[pp];
    }
    __syncthreads();
    if (kb + 1 < 12) {
      int kn = (kb + 1) * 64;
#pragma unroll
      for (int pp = 0; pp < 4; ++pp) {
        int row = pp * 32 + r0;
        ra[pp] = *(const bf16x8*)(A + (size_t)(rowBase + row) * DIMF + kn + c0 * 8);
        rb[pp] = *(const bf16x8*)(Bt + (size_t)(colBase + row) * DIMF + kn + c0 * 8);
      }
    }
#pragma unroll
    for (int kk = 0; kk < 2; ++kk) {
      bf16x8 af[4], bfr[4];
#pragma unroll
      for (int m = 0; m < 4; ++m) {
        int row = wr * 64 + m * 16 + lc;
        int ch = kk * 4 + g;
        af[m] = *(const bf16x8*)&As[row * 64 + (((ch ^ (row & 7))) << 3)];
      }
#pragma unroll
      for (int n = 0; n < 4; ++n) {
        int row = wc * 64 + n * 16 + lc;
        int ch = kk * 4 + g;
        bfr[n] = *(const bf16x8*)&Bs[row * 64 + (((ch ^ (row & 7))) << 3)];
      }
#pragma unroll
      for (int m = 0; m < 4; ++m)
#pragma unroll
        for (int n = 0; n < 4; ++n)
          acc[m][n] = __builtin_amdgcn_mfma_f32_16x16x32_bf16(af[m], bfr[n], acc[m][n], 0, 0, 0);
    }
  }

  // ---- epilogue (C/D frag: col = lc, row = g*4 + reg) ----
  if (MODE == 0 || MODE == 2) {
    unsigned short* Ko = (unsigned short*)outp;
#pragma unroll
    for (int m = 0; m < 4; ++m)
#pragma unroll
      for (int n = 0; n < 4; ++n)
#pragma unroll
        for (int r = 0; r < 4; ++r) {
          int p = rowBase + wr * 64 + m * 16 + g * 4 + r;
          int f = colBase + wc * 64 + n * 16 + lc;
          int d = f & 63, h = f >> 6;
          float v = acc[m][n][r];
          float vo = __shfl_xor(v, 1);
          if (MODE == 0) {
            int b = p >> 12, nkv = p & 4095;
            float sn = rope[nkv * 128 + d], cs = rope[nkv * 128 + 64 + d];
            float o = (d & 1) ? fmaf(vo, sn, v * cs) : fmaf(-vo, sn, v * cs);
            Ko[((size_t)(b * NHEAD + h) * NKV + nkv) * 64 + d] = f2bf(o);
          } else {
            int b = p >> 8, nq = p & 255;
            float sn = rope[nq * 128 + d], cs = rope[nq * 128 + 64 + d];
            float o = (d & 1) ? fmaf(vo, sn, v * cs) : fmaf(-vo, sn, v * cs);
            Ko[((size_t)(b * NHEAD + h) * NQ + nq) * 64 + d] = f2bf(o * 0.125f);
          }
        }
  } else if (MODE == 1) {
    unsigned short* Vt = (unsigned short*)outp;
#pragma unroll
    for (int m = 0; m < 4; ++m)
#pragma unroll
      for (int n = 0; n < 4; ++n) {
        int p0 = rowBase + wr * 64 + m * 16 + g * 4;   // 4 consecutive rows
        int b = p0 >> 12, nkv0 = p0 & 4095;
        int f = colBase + wc * 64 + n * 16 + lc;
        int d = f & 63, h = f >> 6;
        us4 w{f2bf(acc[m][n][0]), f2bf(acc[m][n][1]), f2bf(acc[m][n][2]), f2bf(acc[m][n][3])};
        *(us4*)&Vt[((size_t)(b * NHEAD + h) * 64 + d) * NKV + nkv0] = w;
      }
  } else {
    float* Co = (float*)outp;
#pragma unroll
    for (int m = 0; m < 4; ++m)
#pragma unroll
      for (int n = 0; n < 4; ++n)
#pragma unroll
        for (int r = 0; r < 4; ++r) {
          int p = rowBase + wr * 64 + m * 16 + g * 4 + r;
          int f = colBase + wc * 64 + n * 16 + lc;
          Co[(size_t)p * DIMF + f] = acc[m][n][r];
        }
  }
}

// ---------------- flash attention (R2) --------------------------------------
// grid 768: logical = XCD-bijective swizzle of blockIdx; qt = logical&3 (64-row
// q tile), bh = logical>>2. 2 waves x 32 q-rows. LDS 40KB -> 4 blocks/CU.
__launch_bounds__(128, 2)
__global__ void attn_kernel(const unsigned short* __restrict__ Qb,
                            const unsigned short* __restrict__ Kb,
                            const unsigned short* __restrict__ Vtb,
                            unsigned short* __restrict__ Ob) {
  __shared__ unsigned short Ks[128 * 64];    // [kv][d]   16KB (swizzled chunks)
  __shared__ unsigned short Vts[64 * 128];   // [d][kv]   16KB
  __shared__ unsigned short Ps[2][16 * 128]; // per-wave P (16 q-rows)  8KB
  const int logical = (blockIdx.x & 7) * 96 + (blockIdx.x >> 3);  // 768%8==0: bijective
  const int qt = logical & 3, bh = logical >> 2;
  const int b = bh / NHEAD, h = bh % NHEAD;
  const int t = threadIdx.x;
  const int lane = t & 63, w = t >> 6;
  const int g = lane >> 4, lc = lane & 15;
  const int qbase = qt * 64;

  const f32x4 z4 = {0.f, 0.f, 0.f, 0.f};
  bf16x8 qf[2][2];
#pragma unroll
  for (int m = 0; m < 2; ++m)
#pragma unroll
    for (int kk = 0; kk < 2; ++kk) {
      int row = qbase + w * 32 + m * 16 + lc;
      qf[m][kk] = *(const bf16x8*)(Qb + ((size_t)bh * NQ + row) * 64 + kk * 32 + g * 8);
    }

  f32x4 oacc[2][4];
  float mrun[2][4], lrun[2][4];
#pragma unroll
  for (int m = 0; m < 2; ++m)
#pragma unroll
    for (int r = 0; r < 4; ++r) { mrun[m][r] = -1e30f; lrun[m][r] = 0.f; }
#pragma unroll
  for (int m = 0; m < 2; ++m)
#pragma unroll
    for (int n = 0; n < 4; ++n) oacc[m][n] = z4;

  // staging registers (T14: issue early, ds_write late)
  const int r0 = t >> 3, c0 = t & 7;    // K tile: 16 rows x 8 chunks
  const int d0 = t >> 4, cv = t & 15;   // V tile: 8 d-rows x 16 chunks
  bf16x8 rk[8], rv[8];

#define LOAD_TILE(KT)                                                                   \
  do {                                                                                  \
    const int kvb = (KT) * 128;                                                         \
    _Pragma("unroll")                                                                   \
    for (int pp = 0; pp < 8; ++pp)                                                      \
      rk[pp] = *(const bf16x8*)(Kb + ((size_t)bh * NKV + kvb + pp * 16 + r0) * 64 + c0 * 8); \
    _Pragma("unroll")                                                                   \
    for (int pp = 0; pp < 8; ++pp)                                                      \
      rv[pp] = *(const bf16x8*)(Vtb + ((size_t)bh * 64 + pp * 8 + d0) * NKV + kvb + cv * 8); \
  } while (0)

  LOAD_TILE(0);

  for (int kt = 0; kt < 32; ++kt) {
    __syncthreads();   // prev tile's LDS reads done
    // write staged regs -> LDS (swizzled)
#pragma unroll
    for (int pp = 0; pp < 8; ++pp) {
      int row = pp * 16 + r0;
      *(bf16x8*)&Ks[row * 64 + ((c0 ^ (row & 7)) << 3)] = rk[pp];
    }
#pragma unroll
    for (int pp = 0; pp < 8; ++pp) {
      int d = pp * 8 + d0;
      *(bf16x8*)&Vts[d * 128 + ((cv ^ (d & 7)) << 3)] = rv[pp];
    }
    if (kt + 1 < 32) LOAD_TILE(kt + 1);   // prefetch next tile (hides HBM latency)
    __syncthreads();   // staging visible

#pragma unroll
    for (int m = 0; m < 2; ++m) {
      // S = Q K^T for this 16-row block: 16 rows x 128 cols
      f32x4 s[8];
#pragma unroll
      for (int nf = 0; nf < 8; ++nf) s[nf] = z4;
#pragma unroll
      for (int kk = 0; kk < 2; ++kk)
#pragma unroll
        for (int nf = 0; nf < 8; ++nf) {
          int row = nf * 16 + lc;
          int ch = kk * 4 + g;
          bf16x8 kf = *(const bf16x8*)&Ks[row * 64 + ((ch ^ (row & 7)) << 3)];
          s[nf] = __builtin_amdgcn_mfma_f32_16x16x32_bf16(qf[m][kk], kf, s[nf], 0, 0, 0);
        }

      // online softmax (rows = g*4+r, cols distributed over nf,lc)
      float mx[4];
#pragma unroll
      for (int r = 0; r < 4; ++r) {
        float v = s[0][r];
#pragma unroll
        for (int nf = 1; nf < 8; ++nf) v = fmaxf(v, s[nf][r]);
        mx[r] = v;
      }
#pragma unroll
      for (int r = 0; r < 4; ++r) {
        mx[r] = fmaxf(mx[r], __shfl_xor(mx[r], 1));
        mx[r] = fmaxf(mx[r], __shfl_xor(mx[r], 2));
        mx[r] = fmaxf(mx[r], __shfl_xor(mx[r], 4));
        mx[r] = fmaxf(mx[r], __shfl_xor(mx[r], 8));
      }
#pragma unroll
      for (int r = 0; r < 4; ++r) {
        float nm = fmaxf(mrun[m][r], mx[r]);
        float al = __expf(mrun[m][r] - nm);
        mrun[m][r] = nm;
        float ls = 0.f;
#pragma unroll
        for (int nf = 0; nf < 8; ++nf) {
          float p = __expf(s[nf][r] - nm);
          s[nf][r] = p;
          ls += p;
        }
        ls += __shfl_xor(ls, 1);
        ls += __shfl_xor(ls, 2);
        ls += __shfl_xor(ls, 4);
        ls += __shfl_xor(ls, 8);
        lrun[m][r] = lrun[m][r] * al + ls;
#pragma unroll
        for (int nf = 0; nf < 4; ++nf) oacc[m][nf][r] *= al;
      }
      // P -> LDS (wave-private, no barrier needed before PV: lgkmcnt orders)
#pragma unroll
      for (int nf = 0; nf < 8; ++nf)
#pragma unroll
        for (int r = 0; r < 4; ++r) {
          int rowl = g * 4 + r;
          int col = nf * 16 + lc;
          int ch = col >> 3;
          Ps[w][rowl * 128 + ((ch ^ (rowl & 7)) << 3) + (col & 7)] = f2bf(s[nf][r]);
        }

      // O(m) += P V
#pragma unroll
      for (int kk = 0; kk < 4; ++kk) {
        int chp = kk * 4 + g;
        bf16x8 pa = *(const bf16x8*)&Ps[w][lc * 128 + ((chp ^ (lc & 7)) << 3)];
#pragma unroll
        for (int nf = 0; nf < 4; ++nf) {
          int row = nf * 16 + lc;
          bf16x8 vf = *(const bf16x8*)&Vts[row * 128 + ((chp ^ (row & 7)) << 3)];
          oacc[m][nf] = __builtin_amdgcn_mfma_f32_16x16x32_bf16(pa, vf, oacc[m][nf], 0, 0, 0);
        }
      }
    }
  }
#undef LOAD_TILE

  // epilogue: normalize, write O [b][q][h*64+d] bf16
#pragma unroll
  for (int m = 0; m < 2; ++m) {
    float inv[4];
#pragma unroll
    for (int r = 0; r < 4; ++r) inv[r] = 1.0f / lrun[m][r];
#pragma unroll
    for (int nf = 0; nf < 4; ++nf)
#pragma unroll
      for (int r = 0; r < 4; ++r) {
        int q = qbase + w * 32 + m * 16 + g * 4 + r;
        int col = h * 64 + nf * 16 + lc;
        Ob[((size_t)b * NQ + q) * DIMF + col] = f2bf(oacc[m][nf][r] * inv[r]);
      }
  }
}

// ---------------- launch ----------------------------------------------------
extern "C" void kernel_launch(void* const* d_in, const int* in_sizes, int n_in,
                              void* d_out, int out_size, void* d_ws, size_t ws_size,
                              hipStream_t stream) {
  const float* x      = (const float*)d_in[0];
  const float* ctx    = (const float*)d_in[1];
  const float* rope_q = (const float*)d_in[2];
  const float* rope_k = (const float*)d_in[3];
  const float* Wq     = (const float*)d_in[4];
  const float* Wk     = (const float*)d_in[5];
  const float* Wv     = (const float*)d_in[6];
  const float* Wo     = (const float*)d_in[7];

  char* ws = (char*)d_ws;
  // workspace layout (bytes)
  const size_t SZ_CTXB = (size_t)NB * NKV * DIMF * 2;   // 100,663,296
  const size_t SZ_XB   = (size_t)NB * NQ * DIMF * 2;    // 6,291,456
  const size_t SZ_WT   = (size_t)DIMF * DIMF * 2;       // 1,179,648
  unsigned short* ctxb = (unsigned short*)(ws);
  unsigned short* ob   = (unsigned short*)(ws);                       // alias ctxb (dead after V-GEMM)
  unsigned short* xb   = (unsigned short*)(ws + SZ_CTXB);
  unsigned short* wkt  = (unsigned short*)(ws + SZ_CTXB + SZ_XB);
  unsigned short* wvt  = (unsigned short*)(ws + SZ_CTXB + SZ_XB + SZ_WT);
  unsigned short* wqt  = (unsigned short*)(ws + SZ_CTXB + SZ_XB + 2 * SZ_WT);
  unsigned short* wot  = (unsigned short*)(ws + SZ_CTXB + SZ_XB + 3 * SZ_WT);
  unsigned short* kb   = (unsigned short*)(ws + SZ_CTXB + SZ_XB + 4 * SZ_WT);
  unsigned short* vtb  = (unsigned short*)(ws + SZ_CTXB + SZ_XB + 4 * SZ_WT + SZ_CTXB);
  unsigned short* qb   = (unsigned short*)(ws + SZ_CTXB + SZ_XB + 4 * SZ_WT + 2 * SZ_CTXB);

  cvt_kernel<<<dim3(2048), dim3(256), 0, stream>>>(ctx, ctxb, NB * NKV * DIMF);
  cvt_kernel<<<dim3(1024), dim3(256), 0, stream>>>(x, xb, NB * NQ * DIMF);
  twt_kernel<<<dim3(24, 24, 4), dim3(32, 8), 0, stream>>>(Wk, Wv, Wq, Wo, wkt, wvt, wqt, wot);

  gemm_kernel<0><<<dim3(512, 6), dim3(256), 0, stream>>>(ctxb, wkt, kb, rope_k);
  gemm_kernel<1><<<dim3(512, 6), dim3(256), 0, stream>>>(ctxb, wvt, vtb, nullptr);
  gemm_kernel<2><<<dim3(32, 6), dim3(256), 0, stream>>>(xb, wqt, qb, rope_q);

  attn_kernel<<<dim3(768), dim3(128), 0, stream>>>(qb, kb, vtb, ob);

  gemm_kernel<3><<<dim3(32, 6), dim3(256), 0, stream>>>(ob, wot, d_out, nullptr);
}